// Round 13
// baseline (575.154 us; speedup 1.0000x reference)
//
#include <hip/hip_runtime.h>

#define NNODES 100000
#define F 256
#define NBKT ((NNODES + 127) / 128)    // 782 buckets of 128 src nodes
#define BKT_CAP 5040                   // mean 4092, +14.8 sigma; LDS 40.8KB -> 4 blk/CU
#define CHUNK_A 8192                   // edges per bin_edges block

typedef unsigned short u16;
typedef unsigned int   u32;
typedef __attribute__((ext_vector_type(8))) short short8v;          // 8 bf16
typedef __attribute__((ext_vector_type(8))) unsigned short ushort8; // 8 bf16 bits
typedef __attribute__((ext_vector_type(4))) float f32x4;
typedef __attribute__((ext_vector_type(2))) float f32x2;

// async global->LDS, 16B per lane; dst must be wave-uniform base (+lane*16 by HW)
#define GLDS(g, l) __builtin_amdgcn_global_load_lds(                                \
    (const __attribute__((address_space(1))) void*)(g),                             \
    (__attribute__((address_space(3))) void*)(l), 16, 0, 0)

__device__ __forceinline__ u16 f2bf(float f) {
    u32 u = __float_as_uint(f);
    u32 r = u + 0x7FFFu + ((u >> 16) & 1u);   // round-to-nearest-even
    return (u16)(r >> 16);
}

// ---------------- cast W -> bf16 + init bucket cursors (fused) ----------------
__global__ __launch_bounds__(256) void cast_w_init(const float* __restrict__ W,
                                                   u16* __restrict__ Wb,
                                                   int* __restrict__ cur) {
    int i = blockIdx.x * 256 + threadIdx.x;
    if (i < F * F / 4) {
        float4 w = ((const float4*)W)[i];
        ushort4 o;
        o.x = f2bf(w.x); o.y = f2bf(w.y); o.z = f2bf(w.z); o.w = f2bf(w.w);
        ((ushort4*)Wb)[i] = o;
    }
    if (i < NBKT) cur[i] = i * BKT_CAP;
}

// ---------------- cast X -> bf16 (streaming) ----------------
__global__ __launch_bounds__(256) void cast_x(const float* __restrict__ X,
                                              u16* __restrict__ Xb, int total4) {
    int i = blockIdx.x * 256 + threadIdx.x;
    if (i >= total4) return;
    float4 x = ((const float4*)X)[i];
    ushort4 o;
    o.x = f2bf(x.x); o.y = f2bf(x.y); o.z = f2bf(x.z); o.w = f2bf(x.w);
    ((ushort4*)Xb)[i] = o;
}

// ---------------- GEMM: Yb = bf16( Xb @ Wb^T ) via MFMA, LDS-staged ----------
// global_load_lds width=16 staging (r10: -14us vs reg-staging). LDS dest linear
// (wave-uniform base + lane*16), swizzle on per-lane GLOBAL source address.
__global__ __launch_bounds__(256) void gemm_mfma(const u16* __restrict__ Xb,
                                                 const u16* __restrict__ Wb,
                                                 u16* __restrict__ Yb) {
    __shared__ u16 As[128 * 128];   // 32 KB
    __shared__ u16 Bs[128 * 128];   // 32 KB
    const int tid  = threadIdx.x;
    const int wv   = tid >> 6;
    const int lane = tid & 63;
    const int lm   = lane & 15;
    const int kg   = lane >> 4;
    const int m0   = blockIdx.x * 128;
    const int n0   = blockIdx.y * 128;

    const u32 csb = (u32)(((tid & 15) ^ ((tid >> 4) & 7)) * 16);
    const u32 rbb = (u32)((tid >> 4) * 512);
    const char* gA0 = (const char*)Xb + (size_t)m0 * 512 + rbb + csb;
    const char* gB0 = (const char*)Wb + (size_t)n0 * 512 + rbb + csb;
    const u32 wbase = (u32)(wv * 1024);      // wave-uniform LDS byte base

    f32x4 acc[2][8];
#pragma unroll
    for (int t = 0; t < 2; ++t)
#pragma unroll
        for (int u = 0; u < 8; ++u) acc[t][u] = (f32x4){0.f, 0.f, 0.f, 0.f};

#pragma unroll
    for (int kt = 0; kt < 2; ++kt) {
        if (kt) __syncthreads();          // protect LDS before overwrite
#pragma unroll
        for (int i = 0; i < 8; ++i) {     // 16 async 16B/lane issues, one drain
            GLDS(gA0 + kt * 256 + i * 8192, (char*)As + i * 4096 + wbase);
            GLDS(gB0 + kt * 256 + i * 8192, (char*)Bs + i * 4096 + wbase);
        }
        __syncthreads();                  // drains vmcnt + barrier
#pragma unroll
        for (int s = 0; s < 4; ++s) {     // 4 k-steps of 32 per K-tile
            short8v aF[2];
#pragma unroll
            for (int t = 0; t < 2; ++t) {
                int r = wv * 32 + t * 16 + lm;
                int c = (s * 4 + kg) ^ (r & 7);
                aF[t] = *(const short8v*)&As[r * 128 + c * 8];
            }
            short8v bF[8];
#pragma unroll
            for (int u = 0; u < 8; ++u) {
                int r = u * 16 + lm;
                int c = (s * 4 + kg) ^ (r & 7);
                bF[u] = *(const short8v*)&Bs[r * 128 + c * 8];
            }
#pragma unroll
            for (int t = 0; t < 2; ++t)
#pragma unroll
                for (int u = 0; u < 8; ++u)
                    acc[t][u] = __builtin_amdgcn_mfma_f32_16x16x32_bf16(aF[t], bF[u], acc[t][u], 0, 0, 0);
        }
    }

    // D layout (16x16x32): col = lane&15, row = (lane>>4)*4 + i
#pragma unroll
    for (int t = 0; t < 2; ++t) {
        int rbase = m0 + wv * 32 + t * 16 + kg * 4;
#pragma unroll
        for (int i = 0; i < 4; ++i) {
            int row = rbase + i;
            if (row < NNODES) {
#pragma unroll
                for (int u = 0; u < 8; ++u)
                    Yb[(size_t)row * F + n0 + u * 16 + lm] = f2bf(acc[t][u][i]);
            }
        }
    }
}

// ---------------- Phase A: bin edges into 128-node buckets ----------------
// temp[pos] = ( (src&127)<<20 | dst , val_bits ), bucket-strided regions.
__global__ __launch_bounds__(256) void bin_edges(const int* __restrict__ src,
                                                 const int* __restrict__ dst,
                                                 const float* __restrict__ val,
                                                 int* __restrict__ cur,
                                                 int2* __restrict__ temp,
                                                 int n_edges) {
    __shared__ int hist[NBKT];
    __shared__ int bas[NBKT];
    const int e0 = blockIdx.x * CHUNK_A;
    for (int i = threadIdx.x; i < NBKT; i += 256) hist[i] = 0;
    __syncthreads();

    u32 lpk[32];
#pragma unroll
    for (int k = 0; k < 32; ++k) {
        int e = e0 + k * 256 + threadIdx.x;
        if (e < n_edges) {
            int s = src[e];
            int bkt = s >> 7;
            int l = atomicAdd(&hist[bkt], 1);          // < 8192, fits 13 bits
            lpk[k] = (u32)l | ((u32)(s & 127) << 13) | ((u32)bkt << 20);
        }
    }
    __syncthreads();
    for (int i = threadIdx.x; i < NBKT; i += 256) {
        int c = hist[i];
        bas[i] = c ? atomicAdd(&cur[i], c) : 0;
    }
    __syncthreads();
#pragma unroll
    for (int k = 0; k < 32; ++k) {
        int e = e0 + k * 256 + threadIdx.x;
        if (e < n_edges) {
            u32 p   = lpk[k];
            int bkt = (int)(p >> 20);
            int pos = bas[bkt] + (int)(p & 0x1FFFu);
            int sl  = (int)((p >> 13) & 127u);
            if (pos < (bkt + 1) * BKT_CAP)             // overflow guard (P~1e-44)
                temp[pos] = make_int2((sl << 20) | dst[e], __float_as_int(val[e]));
        }
    }
}

// ---------------- Fused: per-bucket node sort (in LDS) + gather + bias -------
// One block per bucket. Stage bucket edges into REGISTERS (20 int2/thread,
// unrolled -> no scratch), LDS histogram w/ returned local pos, 128-scan,
// write sorted (dst*512, val) into pk LDS, then gather straight from LDS.
// Removes pack write+read (51 MB), nodeseg, one launch, and the global pack
// load from the gather dependency chain (LDS broadcast read instead).
__global__ __launch_bounds__(256) void sort_gather(const int* __restrict__ cur,
                                                   const int2* __restrict__ temp,
                                                   const u16* __restrict__ Yb,
                                                   const float* __restrict__ bias,
                                                   float* __restrict__ out) {
    __shared__ int2 pk[BKT_CAP];     // 39.4 KB
    __shared__ int h[128];
    const int b = blockIdx.x;
    const int base = b * BKT_CAP;
    const int tid = threadIdx.x;
    int cnt = cur[b] - base;
    if (cnt > BKT_CAP) cnt = BKT_CAP;   // overflow guard

    if (tid < 128) h[tid] = 0;
    __syncthreads();

    int2 ed[20];
    int  lp[20];
#pragma unroll
    for (int q = 0; q < 20; ++q) {       // BKT_CAP/256 = 19.7 -> 20 slots
        int j = q * 256 + tid;
        if (j < cnt) {
            int2 t = temp[base + j];
            ed[q] = t;
            lp[q] = atomicAdd(&h[t.x >> 20], 1);
        }
    }
    __syncthreads();
    // inclusive scan over h[0..127]
    for (int off = 1; off < 128; off <<= 1) {
        int x = 0;
        if (tid < 128 && tid >= off) x = h[tid - off];
        __syncthreads();
        if (tid < 128) h[tid] += x;
        __syncthreads();
    }
    // scatter into pk at excl(loc) + lp   (pk.x = dst*512 byte offset)
#pragma unroll
    for (int q = 0; q < 20; ++q) {
        int j = q * 256 + tid;
        if (j < cnt) {
            int loc = ed[q].x >> 20;
            int st  = loc ? h[loc - 1] : 0;
            pk[st + lp[q]] = make_int2((ed[q].x & 0xFFFFF) << 9, ed[q].y);
        }
    }
    __syncthreads();

    // gather: wave wv handles local nodes wv*32 .. wv*32+31
    const int wv   = tid >> 6;
    const int lane = tid & 63;
    const int half = lane >> 5;
    const int l5   = lane & 31;
    const u32 loff = (u32)l5 * 16u;
    const char* Ybc = (const char*)Yb;
    const int col = l5 * 8 + half * 4;
    const float4 bv = *(const float4*)&bias[col];

    for (int k = 0; k < 32; ++k) {
        int ln   = wv * 32 + k;
        int node = b * 128 + ln;
        if (node >= NNODES) break;       // only last bucket
        int beg = ln ? h[ln - 1] : 0;
        int end = h[ln];

        f32x2 acc2[4];
#pragma unroll
        for (int i = 0; i < 4; ++i) acc2[i] = (f32x2){0.f, 0.f};

        for (int j = beg; j < end; j += 16) {   // 8 pairs = 16 edges per iter
            u32 off8[8];
            float v[8];
            ushort8 y[8];
#pragma unroll
            for (int q = 0; q < 8; ++q) {
                int idx  = j + 2 * q + half;
                int safe = idx < end ? idx : end - 1;
                int2 p = pk[safe];               // LDS broadcast per half
                off8[q] = (u32)p.x;
                v[q]    = (idx < end) ? __int_as_float(p.y) : 0.f;
            }
#pragma unroll
            for (int q = 0; q < 8; ++q)
                y[q] = *(const ushort8*)(Ybc + (off8[q] + loff));
#pragma unroll
            for (int q = 0; q < 8; ++q) {
                f32x2 vv; vv[0] = v[q]; vv[1] = v[q];
                const u32* yp = (const u32*)&y[q];
#pragma unroll
                for (int i = 0; i < 4; ++i) {
                    u32 pb = yp[i];
                    f32x2 yy;
                    yy[0] = __uint_as_float(pb << 16);
                    yy[1] = __uint_as_float(pb & 0xFFFF0000u);
                    acc2[i] = __builtin_elementwise_fma(yy, vv, acc2[i]);
                }
            }
        }

        float acc[8];
#pragma unroll
        for (int i = 0; i < 4; ++i) { acc[2 * i] = acc2[i][0]; acc[2 * i + 1] = acc2[i][1]; }
#pragma unroll
        for (int i = 0; i < 8; ++i) acc[i] += __shfl_xor(acc[i], 32);

        f32x4 o;
        o[0] = acc[half * 4 + 0] + bv.x;
        o[1] = acc[half * 4 + 1] + bv.y;
        o[2] = acc[half * 4 + 2] + bv.z;
        o[3] = acc[half * 4 + 3] + bv.w;
        __builtin_nontemporal_store(o, (f32x4*)&out[(size_t)node * F + col]);
    }
}

extern "C" void kernel_launch(void* const* d_in, const int* in_sizes, int n_in,
                              void* d_out, int out_size, void* d_ws, size_t ws_size,
                              hipStream_t stream) {
    const float* X        = (const float*)d_in[0];
    const int*   edge_src = (const int*)d_in[1];
    const int*   edge_dst = (const int*)d_in[2];
    const float* edge_val = (const float*)d_in[3];
    const float* W        = (const float*)d_in[4];
    const float* b        = (const float*)d_in[5];
    float*       out      = (float*)d_out;
    const int n_edges     = in_sizes[1];

    // Workspace (~103 MB): Yb | temp(+pad) | Wb | cur.  Xb (51.25 MB incl.
    // 96-row OOB pad) overlays temp+pad: Xb dead after gemm; temp written after.
    char* base = (char*)d_ws;
    const size_t ybBytes   = (size_t)NNODES * F * sizeof(u16);        // 51.2 MB
    const size_t xbBytes   = (size_t)100096 * F * sizeof(u16);        // 51.25 MB
    u16*  Yb      = (u16*)base;
    int2* temp    = (int2*)(base + ybBytes);                          // 31.53 MB used
    u16*  Xb      = (u16*)temp;                                       // overlay
    u16*  Wb      = (u16*)(base + ybBytes + xbBytes);
    int*  cur     = (int*)((char*)Wb + (size_t)F * F * sizeof(u16));

    // 1) W cast + cursor init (fused); X cast
    cast_w_init<<<(F * F / 4 + 255) / 256, 256, 0, stream>>>(W, Wb, cur);
    int xt4 = NNODES * F / 4;
    cast_x<<<(xt4 + 255) / 256, 256, 0, stream>>>(X, Xb, xt4);

    // 2) Yb = bf16(Xb @ Wb^T) via LDS-staged MFMA (async global_load_lds)
    dim3 ggrid((NNODES + 127) / 128, F / 128);
    gemm_mfma<<<ggrid, 256, 0, stream>>>(Xb, Wb, Yb);

    // 3) bin edges into bucket-strided temp
    bin_edges<<<(n_edges + CHUNK_A - 1) / CHUNK_A, 256, 0, stream>>>(edge_src, edge_dst, edge_val,
                                                                     cur, temp, n_edges);

    // 4) fused per-bucket sort + gather + bias
    sort_gather<<<NBKT, 256, 0, stream>>>(cur, temp, Yb, b, out);
}